// Round 3
// baseline (5576.460 us; speedup 1.0000x reference)
//
#include <hip/hip_runtime.h>
#include <math.h>

#define N_MEM 100
#define C_DIM 768
#define HW_SZ 2304            // 48*48
#define TEMP 0.07f
#define EPS_F 1e-8f
#define LAM_F 0.01f           // 1/N_MEM
#define NORM_EPS 1e-12f

#define CH 128                          // c-chunk staged in LDS
#define CH_F4 (CH * N_MEM / 4)          // 3200 float4 = 51.2 KB

// -------------------------------------------------------------------------
// Kernel 1: L2-normalize each memory row and store TRANSPOSED: mT[c][n].
// -------------------------------------------------------------------------
__global__ __launch_bounds__(64) void prep_mT(const float* __restrict__ mem,
                                              float* __restrict__ mT) {
    const int n = blockIdx.x;        // 0..99  (one wave per memory row)
    const int lane = threadIdx.x;    // 0..63
    const float* row = mem + n * C_DIM;

    float ss = 0.f;
    for (int c = lane; c < C_DIM; c += 64) {
        float v = row[c];
        ss = fmaf(v, v, ss);
    }
    for (int off = 32; off > 0; off >>= 1)
        ss += __shfl_down(ss, off);
    float norm = sqrtf(__shfl(ss, 0));
    float inv = 1.0f / fmaxf(norm, NORM_EPS);

    for (int c = lane; c < C_DIM; c += 64)
        mT[c * N_MEM + n] = row[c] * inv;
}

// -------------------------------------------------------------------------
// Kernel 2: fused  scores -> softmax -> shrinkage -> renorm -> reconstruct.
// 256-thread blocks (4 waves); one thread per spatial row. mT is staged
// chunk-by-chunk into LDS so the per-c 100-float mrow read is an LDS
// broadcast (~12 cy) instead of a wave-uniform VMEM load (~200 cy).
//
// NUMERICS CONTRACT (R1/R2 passed at absmax 4.94e-3, threshold 5.27e-3):
// every acc[n] and ss accumulates c = 0..767 strictly sequentially with
// fmaf; softmax/shrinkage sequence unchanged. LDS staging only moves
// WHERE mrow is read from, never the FMA order.
// -------------------------------------------------------------------------
__global__ __launch_bounds__(256, 3) void memmod_main(const float* __restrict__ F,
                                                      const float* __restrict__ mT,
                                                      float* __restrict__ Fhat,
                                                      float* __restrict__ What) {
    __shared__ float4 lds4[CH_F4];
    const float* lds = (const float*)lds4;

    const int tid = threadIdx.x;                    // 0..255
    const int blk = blockIdx.x;                     // 0..575
    const int b   = blk / 9;                        // 9 blocks per image
    const int hw  = (blk % 9) * 256 + tid;          // 0..2303
    const size_t plane = (size_t)b * C_DIM * HW_SZ + hw;

    float acc[N_MEM];
#pragma unroll
    for (int n = 0; n < N_MEM; ++n) acc[n] = 0.f;
    float ss = 0.f;

    // ---- scores pass: acc[n] = sum_c z[c]*m_norm[n][c];  ss = |z|^2 ----
    const float* Fp = F + plane;
    for (int c0 = 0; c0 < C_DIM; c0 += CH) {
        __syncthreads();                             // prior chunk reads done
        const float4* src4 = reinterpret_cast<const float4*>(mT + c0 * N_MEM);
        for (int i = tid; i < CH_F4; i += 256)       // cooperative stage
            lds4[i] = src4[i];
        __syncthreads();

        for (int cc = 0; cc < CH; ++cc) {
            const float zc = Fp[(size_t)(c0 + cc) * HW_SZ];  // coalesced
            ss = fmaf(zc, zc, ss);
            const float* mrow = lds + cc * N_MEM;            // LDS broadcast
#pragma unroll
            for (int n = 0; n < N_MEM; ++n)
                acc[n] = fmaf(zc, mrow[n], acc[n]);
        }
    }

    // ---- scale by 1/(||z||*T), softmax (max-subtracted) — UNCHANGED ----
    const float scale = 1.0f / (fmaxf(sqrtf(ss), NORM_EPS) * TEMP);
    float mx = -INFINITY;
#pragma unroll
    for (int n = 0; n < N_MEM; ++n) {
        acc[n] *= scale;
        mx = fmaxf(mx, acc[n]);
    }
    float sum = 0.f;
#pragma unroll
    for (int n = 0; n < N_MEM; ++n) {
        acc[n] = expf(acc[n] - mx);
        sum += acc[n];
    }
    float s2 = 0.f;
#pragma unroll
    for (int n = 0; n < N_MEM; ++n) {
        const float w = acc[n] / sum;
        const float d = w - LAM_F;
        const float wh = (d > 0.f ? d : 0.f) * w / (fabsf(d) + EPS_F);
        acc[n] = wh;
        s2 += wh;
    }
    const float s2c = fmaxf(s2, EPS_F);
#pragma unroll
    for (int n = 0; n < N_MEM; ++n)
        acc[n] = acc[n] / s2c;

    // ---- emit w_hat_spatial [b][p][n]: 25 x float4 stores ----
    float* wout = What + (size_t)(b * HW_SZ + hw) * N_MEM;
#pragma unroll
    for (int n = 0; n < N_MEM; n += 4) {
        float4 v = make_float4(acc[n], acc[n + 1], acc[n + 2], acc[n + 3]);
        *reinterpret_cast<float4*>(wout + n) = v;
    }

    // ---- reconstruction pass: Fhat[b][c][hw] = sum_n w_hat[n]*m[n][c] ----
    float* Fo = Fhat + plane;
    for (int c0 = 0; c0 < C_DIM; c0 += CH) {
        __syncthreads();
        const float4* src4 = reinterpret_cast<const float4*>(mT + c0 * N_MEM);
        for (int i = tid; i < CH_F4; i += 256)
            lds4[i] = src4[i];
        __syncthreads();

#pragma unroll 4
        for (int cc = 0; cc < CH; ++cc) {
            const float* mrow = lds + cc * N_MEM;
            float v = 0.f;
#pragma unroll
            for (int n = 0; n < N_MEM; ++n)
                v = fmaf(acc[n], mrow[n], v);
            Fo[(size_t)(c0 + cc) * HW_SZ] = v;       // coalesced
        }
    }
}

// -------------------------------------------------------------------------
extern "C" void kernel_launch(void* const* d_in, const int* in_sizes, int n_in,
                              void* d_out, int out_size, void* d_ws, size_t ws_size,
                              hipStream_t stream) {
    const float* F   = (const float*)d_in[0];   // [64,768,48,48]
    const float* mem = (const float*)d_in[1];   // [100,768]
    float* Fhat = (float*)d_out;                               // 113,246,208 floats
    float* What = (float*)d_out + (size_t)64 * 768 * 48 * 48;  // 14,745,600 floats
    float* mT   = (float*)d_ws;                                // 76,800 floats

    prep_mT<<<N_MEM, 64, 0, stream>>>(mem, mT);
    memmod_main<<<(64 * HW_SZ) / 256, 256, 0, stream>>>(F, mT, Fhat, What);
}

// Round 4
// 4207.661 us; speedup vs baseline: 1.3253x; 1.3253x over previous
//
#include <hip/hip_runtime.h>
#include <math.h>

#define N_MEM 100
#define C_DIM 768
#define HW_SZ 2304            // 48*48
#define B_SZ  64
#define TEMP 0.07f
#define EPS_F 1e-8f
#define LAM_F 0.01f           // 1/N_MEM
#define NORM_EPS 1e-12f

// -------------------------------------------------------------------------
// Kernel 1: L2-normalize each memory row and store TRANSPOSED: mT[c][n].
// -------------------------------------------------------------------------
__global__ __launch_bounds__(64) void prep_mT(const float* __restrict__ mem,
                                              float* __restrict__ mT) {
    const int n = blockIdx.x;        // 0..99
    const int lane = threadIdx.x;    // 0..63
    const float* row = mem + n * C_DIM;

    float ss = 0.f;
    for (int c = lane; c < C_DIM; c += 64) {
        float v = row[c];
        ss = fmaf(v, v, ss);
    }
    for (int off = 32; off > 0; off >>= 1)
        ss += __shfl_down(ss, off);
    float norm = sqrtf(__shfl(ss, 0));
    float inv = 1.0f / fmaxf(norm, NORM_EPS);

    for (int c = lane; c < C_DIM; c += 64)
        mT[c * N_MEM + n] = row[c] * inv;
}

// -------------------------------------------------------------------------
// softmax + hard-shrinkage + renorm on one row's 100 scores.
// NUMERICS CONTRACT: op sequence identical to R1 (absmax 4.94e-3 passing).
// -------------------------------------------------------------------------
__device__ __forceinline__ void softmax_shrink(float acc[N_MEM], float ss) {
    const float scale = 1.0f / (fmaxf(sqrtf(ss), NORM_EPS) * TEMP);
    float mx = -INFINITY;
#pragma unroll
    for (int n = 0; n < N_MEM; ++n) {
        acc[n] *= scale;
        mx = fmaxf(mx, acc[n]);
    }
    float sum = 0.f;
#pragma unroll
    for (int n = 0; n < N_MEM; ++n) {
        acc[n] = expf(acc[n] - mx);
        sum += acc[n];
    }
    float s2 = 0.f;
#pragma unroll
    for (int n = 0; n < N_MEM; ++n) {
        const float w = acc[n] / sum;
        const float d = w - LAM_F;
        const float wh = (d > 0.f ? d : 0.f) * w / (fabsf(d) + EPS_F);
        acc[n] = wh;
        s2 += wh;
    }
    const float s2c = fmaxf(s2, EPS_F);
#pragma unroll
    for (int n = 0; n < N_MEM; ++n)
        acc[n] = acc[n] / s2c;
}

// -------------------------------------------------------------------------
// Kernel 2: fused pipeline, REGISTER-BLOCKED: each thread owns TWO spatial
// rows (i and i+73728, i.e. batches b and b+32, same hw). Every wave-uniform
// mT value (scalar-cache load) is used twice -> SMEM:VALU ratio halves vs
// R1. Each acc chain still accumulates c=0..767 strictly sequentially with
// the same fmaf sequence -> outputs bit-identical to R1.
// VGPR budget: 2x100 acc + misc ~= 215. NO occupancy floor (R3 lesson:
// a forced floor spilled acc to scratch, 10.6 GB of scratch traffic).
// -------------------------------------------------------------------------
__global__ __launch_bounds__(64) void memmod_main(const float* __restrict__ F,
                                                  const float* __restrict__ mT,
                                                  float* __restrict__ Fhat,
                                                  float* __restrict__ What) {
    const int i   = blockIdx.x * B_SZ + threadIdx.x;   // 0..73727
    const int b0  = i / HW_SZ;                         // 0..31
    const int hw  = i % HW_SZ;
    const size_t plane0 = (size_t)b0 * C_DIM * HW_SZ + hw;
    const size_t plane1 = plane0 + (size_t)32 * C_DIM * HW_SZ;   // batch b0+32

    float acc0[N_MEM], acc1[N_MEM];
#pragma unroll
    for (int n = 0; n < N_MEM; ++n) { acc0[n] = 0.f; acc1[n] = 0.f; }
    float ss0 = 0.f, ss1 = 0.f;

    // ---- scores: two rows per thread, shared uniform mrow ----
    const float* Fp0 = F + plane0;
    const float* Fp1 = F + plane1;
    for (int c = 0; c < C_DIM; ++c) {
        const float z0 = Fp0[(size_t)c * HW_SZ];       // coalesced
        const float z1 = Fp1[(size_t)c * HW_SZ];       // coalesced
        ss0 = fmaf(z0, z0, ss0);
        ss1 = fmaf(z1, z1, ss1);
        const float* mrow = mT + c * N_MEM;            // wave-uniform (SMEM)
#pragma unroll
        for (int n = 0; n < N_MEM; ++n) {
            const float mv = mrow[n];                  // loaded once, used 2x
            acc0[n] = fmaf(z0, mv, acc0[n]);
            acc1[n] = fmaf(z1, mv, acc1[n]);
        }
    }

    // ---- softmax + shrinkage + renorm (identical op sequence) ----
    softmax_shrink(acc0, ss0);
    softmax_shrink(acc1, ss1);

    // ---- emit w_hat_spatial [row][n]: float4 stores ----
    {
        float* w0 = What + (size_t)i * N_MEM;
        float* w1 = What + (size_t)(i + 73728) * N_MEM;
#pragma unroll
        for (int n = 0; n < N_MEM; n += 4) {
            *reinterpret_cast<float4*>(w0 + n) =
                make_float4(acc0[n], acc0[n + 1], acc0[n + 2], acc0[n + 3]);
            *reinterpret_cast<float4*>(w1 + n) =
                make_float4(acc1[n], acc1[n + 1], acc1[n + 2], acc1[n + 3]);
        }
    }

    // ---- reconstruction: two rows per thread, shared uniform mrow ----
    float* Fo0 = Fhat + plane0;
    float* Fo1 = Fhat + plane1;
    for (int c = 0; c < C_DIM; ++c) {
        const float* mrow = mT + c * N_MEM;            // wave-uniform (SMEM)
        float v0 = 0.f, v1 = 0.f;
#pragma unroll
        for (int n = 0; n < N_MEM; ++n) {
            const float mv = mrow[n];
            v0 = fmaf(acc0[n], mv, v0);
            v1 = fmaf(acc1[n], mv, v1);
        }
        Fo0[(size_t)c * HW_SZ] = v0;                   // coalesced
        Fo1[(size_t)c * HW_SZ] = v1;                   // coalesced
    }
}

// -------------------------------------------------------------------------
extern "C" void kernel_launch(void* const* d_in, const int* in_sizes, int n_in,
                              void* d_out, int out_size, void* d_ws, size_t ws_size,
                              hipStream_t stream) {
    const float* F   = (const float*)d_in[0];   // [64,768,48,48]
    const float* mem = (const float*)d_in[1];   // [100,768]
    float* Fhat = (float*)d_out;                               // 113,246,208 floats
    float* What = (float*)d_out + (size_t)64 * 768 * 48 * 48;  // 14,745,600 floats
    float* mT   = (float*)d_ws;                                // 76,800 floats

    prep_mT<<<N_MEM, 64, 0, stream>>>(mem, mT);
    memmod_main<<<(73728 / B_SZ), B_SZ, 0, stream>>>(F, mT, Fhat, What);
}

// Round 5
// 1370.857 us; speedup vs baseline: 4.0679x; 3.0694x over previous
//
#include <hip/hip_runtime.h>
#include <math.h>

#define N_MEM 100
#define C_DIM 768
#define HW_SZ 2304            // 48*48
#define TEMP 0.07f
#define EPS_F 1e-8f
#define LAM_F 0.01f           // 1/N_MEM
#define NORM_EPS 1e-12f

#define NS   4                // n-split: waves per row-group
#define SW   25               // stripe width (N_MEM/NS)
#define SWP  28               // padded stripe (16B-aligned for s_load_dwordx4)
#define ROWS 64               // rows per block
#define SCP  101              // LDS row pad: 101 % 32 = 5, coprime -> 2-way max
#define CB   24               // recon c-tile per register block (192 = 8*24)

// -------------------------------------------------------------------------
// Kernel 1: L2-normalize memory rows, store PADDED-TRANSPOSED:
// mTp[c][ns][SWP], ns-stripe chunks 16B-aligned so wave-uniform reads
// become s_load_dwordx4. Same value bits as R1's mT (same reduction).
// -------------------------------------------------------------------------
__global__ __launch_bounds__(64) void prep_mT(const float* __restrict__ mem,
                                              float* __restrict__ mTp) {
#pragma clang fp contract(off)
    const int n = blockIdx.x;        // 0..99
    const int lane = threadIdx.x;    // 0..63
    const float* row = mem + n * C_DIM;

    float ss = 0.f;
    for (int c = lane; c < C_DIM; c += 64) {
        float v = row[c];
        ss = fmaf(v, v, ss);
    }
    for (int off = 32; off > 0; off >>= 1)
        ss += __shfl_down(ss, off);
    float norm = sqrtf(__shfl(ss, 0));
    float inv = 1.0f / fmaxf(norm, NORM_EPS);

    const int nsI = n / SW, j = n % SW;
    for (int c = lane; c < C_DIM; c += 64)
        mTp[(size_t)c * (NS * SWP) + nsI * SWP + j] = row[c] * inv;
}

// -------------------------------------------------------------------------
// Kernel 2: scores + softmax + shrinkage + renorm -> writes w_hat (What).
// Block = 256 threads = 4 waves over the SAME 64 rows; wave ws owns
// n-stripe [ws*25, ws*25+25). Each acc chain accumulates c = 0..767
// strictly sequentially (bit-identical to R1). Softmax: scores staged to
// read-only LDS; all 4 waves redundantly replay R1's exact op sequence.
// contract(off) pins the mul/sub bits (R1's mul had 2 uses -> never fused).
// -------------------------------------------------------------------------
__global__ __launch_bounds__(256) void memmod_scores(const float* __restrict__ F,
                                                     const float* __restrict__ mTp,
                                                     float* __restrict__ What) {
#pragma clang fp contract(off)
    __shared__ float sc[ROWS][SCP];

    const int tid  = threadIdx.x;
    const int lane = tid & 63;
    const int ws   = tid >> 6;
    const int wsu  = __builtin_amdgcn_readfirstlane(ws);   // force SGPR addr
    const int blk  = blockIdx.x;                 // 0..2303
    const int b    = blk / 36;                   // 36 blocks per image
    const int hw   = (blk % 36) * 64 + lane;     // 0..2303
    const int rowg = b * HW_SZ + hw;             // global row id
    const size_t plane = (size_t)b * C_DIM * HW_SZ + hw;

    float acc[SW];
#pragma unroll
    for (int j = 0; j < SW; ++j) acc[j] = 0.f;
    float ss = 0.f;

    // ---- scores: 25 chains per thread, z loaded per c (L1-shared x4) ----
    const float* Fp = F + plane;
    for (int c = 0; c < C_DIM; ++c) {
        const float zc = Fp[(size_t)c * HW_SZ];                  // coalesced
        ss = fmaf(zc, zc, ss);
        const float* mch = mTp + (size_t)c * (NS * SWP) + wsu * SWP; // s_load
#pragma unroll
        for (int j = 0; j < SW; ++j)
            acc[j] = fmaf(zc, mch[j], acc[j]);
    }

    // ---- stage scores to LDS (read-only afterwards -> race-free) ----
#pragma unroll
    for (int j = 0; j < SW; ++j)
        sc[lane][wsu * SW + j] = acc[j];
    __syncthreads();

    // ---- softmax + shrinkage: R1's exact op sequence, n = 0..99 ----
    const float scale = 1.0f / (fmaxf(sqrtf(ss), NORM_EPS) * TEMP);
    float mx = -INFINITY;
    for (int n = 0; n < N_MEM; ++n)
        mx = fmaxf(mx, sc[lane][n] * scale);
    float sum = 0.f;
    for (int n = 0; n < N_MEM; ++n)
        sum += expf(sc[lane][n] * scale - mx);
    float s2 = 0.f;
    for (int n = 0; n < N_MEM; ++n) {
        const float e = expf(sc[lane][n] * scale - mx);   // same bits as pass 2
        const float w = e / sum;
        const float d = w - LAM_F;
        s2 += (d > 0.f ? d : 0.f) * w / (fabsf(d) + EPS_F);
    }
    const float s2c = fmaxf(s2, EPS_F);

    // ---- own stripe: recompute wh from registers (same bits), emit ----
    float* wout = What + (size_t)rowg * N_MEM + wsu * SW;
#pragma unroll
    for (int j = 0; j < SW; ++j) {
        const float e = expf(acc[j] * scale - mx);
        const float w = e / sum;
        const float d = w - LAM_F;
        const float wh = (d > 0.f ? d : 0.f) * w / (fabsf(d) + EPS_F);
        wout[j] = wh / s2c;
    }
}

// -------------------------------------------------------------------------
// Kernel 3: reconstruction  Fhat[b][c][hw] = sum_n w_hat[row][n]*m[n][c].
// Separate kernel -> own (small) VGPR allocation. w_hat staged to LDS
// coalesced; each wave owns a 192-wide c-stripe of its 64 rows; inner
// register tile 24c x 25n. n ascends 0..99 -> recon chain bit-identical
// to R1 as well.
// -------------------------------------------------------------------------
__global__ __launch_bounds__(256) void memmod_recon(const float* __restrict__ What,
                                                    const float* __restrict__ mTp,
                                                    float* __restrict__ Fhat) {
#pragma clang fp contract(off)
    __shared__ float wh[ROWS][SCP];

    const int tid  = threadIdx.x;
    const int lane = tid & 63;
    const int ws   = tid >> 6;
    const int wsu  = __builtin_amdgcn_readfirstlane(ws);
    const int blk  = blockIdx.x;
    const int b    = blk / 36;
    const int h0   = (blk % 36) * 64;
    const int hw   = h0 + lane;

    // ---- stage 64 rows x 100 w_hat into LDS (coalesced float4 reads) ----
    const float4* src4 =
        reinterpret_cast<const float4*>(What + ((size_t)b * HW_SZ + h0) * N_MEM);
    for (int i = tid; i < ROWS * N_MEM / 4; i += 256) {
        const float4 v = src4[i];
        const int f = i * 4, r = f / N_MEM, n = f % N_MEM;
        wh[r][n] = v.x; wh[r][n + 1] = v.y; wh[r][n + 2] = v.z; wh[r][n + 3] = v.w;
    }
    __syncthreads();

    const size_t plane = (size_t)b * C_DIM * HW_SZ + hw;
    float* Fo = Fhat + plane;
    const int c0w = wsu * (C_DIM / NS);          // 192-wide c-stripe

    for (int cb = 0; cb < C_DIM / NS; cb += CB) {
        float v[CB];
#pragma unroll
        for (int t = 0; t < CB; ++t) v[t] = 0.f;

#pragma unroll
        for (int nc = 0; nc < NS; ++nc) {
            float wr[SW];
#pragma unroll
            for (int j = 0; j < SW; ++j)
                wr[j] = wh[lane][nc * SW + j];    // stride 101 -> 2-way max
#pragma unroll
            for (int t = 0; t < CB; ++t) {
                const float* mch =
                    mTp + (size_t)(c0w + cb + t) * (NS * SWP) + nc * SWP; // s_load
#pragma unroll
                for (int j = 0; j < SW; ++j)
                    v[t] = fmaf(wr[j], mch[j], v[t]);   // n ascending overall
            }
        }
#pragma unroll
        for (int t = 0; t < CB; ++t)
            Fo[(size_t)(c0w + cb + t) * HW_SZ] = v[t];  // coalesced per c
    }
}

// -------------------------------------------------------------------------
extern "C" void kernel_launch(void* const* d_in, const int* in_sizes, int n_in,
                              void* d_out, int out_size, void* d_ws, size_t ws_size,
                              hipStream_t stream) {
    const float* F   = (const float*)d_in[0];   // [64,768,48,48]
    const float* mem = (const float*)d_in[1];   // [100,768]
    float* Fhat = (float*)d_out;                               // 113,246,208 floats
    float* What = (float*)d_out + (size_t)64 * 768 * 48 * 48;  // 14,745,600 floats
    float* mTp  = (float*)d_ws;                                // 768*4*28 floats

    prep_mT<<<N_MEM, 64, 0, stream>>>(mem, mTp);
    memmod_scores<<<2304, 256, 0, stream>>>(F, mTp, What);
    memmod_recon<<<2304, 256, 0, stream>>>(What, mTp, Fhat);
}

// Round 6
// 1288.627 us; speedup vs baseline: 4.3274x; 1.0638x over previous
//
#include <hip/hip_runtime.h>
#include <math.h>

#define N_MEM 100
#define C_DIM 768
#define HW_SZ 2304            // 48*48
#define TEMP 0.07f
#define EPS_F 1e-8f
#define LAM_F 0.01f           // 1/N_MEM
#define NORM_EPS 1e-12f

#define NS   4                // n-split: waves per row-group
#define SW   25               // stripe width (N_MEM/NS)
#define SWP  28               // padded stripe (16B-aligned for s_load_dwordx4)
#define ROWS 64               // rows per block
#define SCP  101              // LDS row pad: 101 % 32 = 5, coprime -> 2-way max
#define CB   24               // recon c-tile per register block (192 = 8*24)
#define ZB   8                // scores c-loop batch: 8 z-loads in flight

// -------------------------------------------------------------------------
// Kernel 1: L2-normalize memory rows, store PADDED-TRANSPOSED:
// mTp[c][ns][SWP], ns-stripe chunks 16B-aligned so wave-uniform reads
// become s_load_dwordx4. Same value bits as R1's mT (same reduction).
// -------------------------------------------------------------------------
__global__ __launch_bounds__(64) void prep_mT(const float* __restrict__ mem,
                                              float* __restrict__ mTp) {
#pragma clang fp contract(off)
    const int n = blockIdx.x;        // 0..99
    const int lane = threadIdx.x;    // 0..63
    const float* row = mem + n * C_DIM;

    float ss = 0.f;
    for (int c = lane; c < C_DIM; c += 64) {
        float v = row[c];
        ss = fmaf(v, v, ss);
    }
    for (int off = 32; off > 0; off >>= 1)
        ss += __shfl_down(ss, off);
    float norm = sqrtf(__shfl(ss, 0));
    float inv = 1.0f / fmaxf(norm, NORM_EPS);

    const int nsI = n / SW, j = n % SW;
    for (int c = lane; c < C_DIM; c += 64)
        mTp[(size_t)c * (NS * SWP) + nsI * SWP + j] = row[c] * inv;
}

// -------------------------------------------------------------------------
// Kernel 2: scores + softmax + shrinkage + renorm -> writes w_hat (What).
// Block = 256 threads = 4 waves over the SAME 64 rows; wave ws owns
// n-stripe [ws*25, ws*25+25).
//
// R6 change: c-loop batched by ZB=8 — the 8 z loads are issued together
// (8 VMEM in flight, progressive vmcnt drain), then the 8 FMA sub-blocks
// run in the ORIGINAL sequential c order. Loads reordered, fmaf chains
// not -> bit-identical to R1/R5 (absmax 4.94e-3 vs threshold 5.27e-3).
// -------------------------------------------------------------------------
__global__ __launch_bounds__(256) void memmod_scores(const float* __restrict__ F,
                                                     const float* __restrict__ mTp,
                                                     float* __restrict__ What) {
#pragma clang fp contract(off)
    __shared__ float sc[ROWS][SCP];

    const int tid  = threadIdx.x;
    const int lane = tid & 63;
    const int ws   = tid >> 6;
    const int wsu  = __builtin_amdgcn_readfirstlane(ws);   // force SGPR addr
    const int blk  = blockIdx.x;                 // 0..2303
    const int b    = blk / 36;                   // 36 blocks per image
    const int hw   = (blk % 36) * 64 + lane;     // 0..2303
    const int rowg = b * HW_SZ + hw;             // global row id
    const size_t plane = (size_t)b * C_DIM * HW_SZ + hw;

    float acc[SW];
#pragma unroll
    for (int j = 0; j < SW; ++j) acc[j] = 0.f;
    float ss = 0.f;

    // ---- scores: batched loads, sequential-c FMA chains ----
    const float* Fp = F + plane;
    for (int c0 = 0; c0 < C_DIM; c0 += ZB) {
        float zb[ZB];                            // static indices -> VGPRs
#pragma unroll
        for (int u = 0; u < ZB; ++u)
            zb[u] = Fp[(size_t)(c0 + u) * HW_SZ];    // 8 coalesced loads in flight
#pragma unroll
        for (int u = 0; u < ZB; ++u) {
            const float zc = zb[u];
            ss = fmaf(zc, zc, ss);
            const float* mch = mTp + (size_t)(c0 + u) * (NS * SWP) + wsu * SWP;
#pragma unroll
            for (int j = 0; j < SW; ++j)
                acc[j] = fmaf(zc, mch[j], acc[j]);
        }
    }

    // ---- stage scores to LDS (read-only afterwards -> race-free) ----
#pragma unroll
    for (int j = 0; j < SW; ++j)
        sc[lane][wsu * SW + j] = acc[j];
    __syncthreads();

    // ---- softmax + shrinkage: R1's exact op sequence, n = 0..99 ----
    const float scale = 1.0f / (fmaxf(sqrtf(ss), NORM_EPS) * TEMP);
    float mx = -INFINITY;
    for (int n = 0; n < N_MEM; ++n)
        mx = fmaxf(mx, sc[lane][n] * scale);
    float sum = 0.f;
    for (int n = 0; n < N_MEM; ++n)
        sum += expf(sc[lane][n] * scale - mx);
    float s2 = 0.f;
    for (int n = 0; n < N_MEM; ++n) {
        const float e = expf(sc[lane][n] * scale - mx);   // same bits as pass 2
        const float w = e / sum;
        const float d = w - LAM_F;
        s2 += (d > 0.f ? d : 0.f) * w / (fabsf(d) + EPS_F);
    }
    const float s2c = fmaxf(s2, EPS_F);

    // ---- own stripe: recompute wh from registers (same bits), emit ----
    float* wout = What + (size_t)rowg * N_MEM + wsu * SW;
#pragma unroll
    for (int j = 0; j < SW; ++j) {
        const float e = expf(acc[j] * scale - mx);
        const float w = e / sum;
        const float d = w - LAM_F;
        const float wh = (d > 0.f ? d : 0.f) * w / (fabsf(d) + EPS_F);
        wout[j] = wh / s2c;
    }
}

// -------------------------------------------------------------------------
// Kernel 3: reconstruction  Fhat[b][c][hw] = sum_n w_hat[row][n]*m[n][c].
// UNCHANGED from R5 (kept fixed for attribution of the scores change).
// -------------------------------------------------------------------------
__global__ __launch_bounds__(256) void memmod_recon(const float* __restrict__ What,
                                                    const float* __restrict__ mTp,
                                                    float* __restrict__ Fhat) {
#pragma clang fp contract(off)
    __shared__ float wh[ROWS][SCP];

    const int tid  = threadIdx.x;
    const int lane = tid & 63;
    const int ws   = tid >> 6;
    const int wsu  = __builtin_amdgcn_readfirstlane(ws);
    const int blk  = blockIdx.x;
    const int b    = blk / 36;
    const int h0   = (blk % 36) * 64;
    const int hw   = h0 + lane;

    // ---- stage 64 rows x 100 w_hat into LDS (coalesced float4 reads) ----
    const float4* src4 =
        reinterpret_cast<const float4*>(What + ((size_t)b * HW_SZ + h0) * N_MEM);
    for (int i = tid; i < ROWS * N_MEM / 4; i += 256) {
        const float4 v = src4[i];
        const int f = i * 4, r = f / N_MEM, n = f % N_MEM;
        wh[r][n] = v.x; wh[r][n + 1] = v.y; wh[r][n + 2] = v.z; wh[r][n + 3] = v.w;
    }
    __syncthreads();

    const size_t plane = (size_t)b * C_DIM * HW_SZ + hw;
    float* Fo = Fhat + plane;
    const int c0w = wsu * (C_DIM / NS);          // 192-wide c-stripe

    for (int cb = 0; cb < C_DIM / NS; cb += CB) {
        float v[CB];
#pragma unroll
        for (int t = 0; t < CB; ++t) v[t] = 0.f;

#pragma unroll
        for (int nc = 0; nc < NS; ++nc) {
            float wr[SW];
#pragma unroll
            for (int j = 0; j < SW; ++j)
                wr[j] = wh[lane][nc * SW + j];    // stride 101 -> 2-way max
#pragma unroll
            for (int t = 0; t < CB; ++t) {
                const float* mch =
                    mTp + (size_t)(c0w + cb + t) * (NS * SWP) + nc * SWP; // s_load
#pragma unroll
                for (int j = 0; j < SW; ++j)
                    v[t] = fmaf(wr[j], mch[j], v[t]);   // n ascending overall
            }
        }
#pragma unroll
        for (int t = 0; t < CB; ++t)
            Fo[(size_t)(c0w + cb + t) * HW_SZ] = v[t];  // coalesced per c
    }
}

// -------------------------------------------------------------------------
extern "C" void kernel_launch(void* const* d_in, const int* in_sizes, int n_in,
                              void* d_out, int out_size, void* d_ws, size_t ws_size,
                              hipStream_t stream) {
    const float* F   = (const float*)d_in[0];   // [64,768,48,48]
    const float* mem = (const float*)d_in[1];   // [100,768]
    float* Fhat = (float*)d_out;                               // 113,246,208 floats
    float* What = (float*)d_out + (size_t)64 * 768 * 48 * 48;  // 14,745,600 floats
    float* mTp  = (float*)d_ws;                                // 768*4*28 floats

    prep_mT<<<N_MEM, 64, 0, stream>>>(mem, mTp);
    memmod_scores<<<2304, 256, 0, stream>>>(F, mTp, What);
    memmod_recon<<<2304, 256, 0, stream>>>(What, mTp, Fhat);
}